// Round 8
// baseline (372.256 us; speedup 1.0000x reference)
//
#include <hip/hip_runtime.h>
#include <hip/hip_bf16.h>

// Mean-shift: 3 iterations of X <- eta * X @ (K/deg) + (1-eta) * X,
// K = exp(2 * X^T X), D=32, N=9216. Fused attention formulation.
// R8: attack the measured-overhead term. R4->R5 slope showed partial traffic
// costs ~1.6 TB/s effective (cross-kernel L2-flush round trip + strided
// gather). Changes: KSEG 7->4 (partials 16.5->9.4 MB/iter; 144/4=36 chunks
// exact), and the reduce kernel is FUSED into msattn via the split-K
// "last block" pattern: one agent-scope release/acquire atomic per block
// (NOT R6's polling storm), the 4th block per query-group reduces warm
// partials and writes Xnext + next iteration's bf16 packs. 7 -> 4 dispatches.
// msattn core = R4's proven shape (8 waves x 16 queries, shared
// double-buffered LDS tiles in MFMA read order, key-interleaved b64 P
// stores) + R6's MFMA-ones den (verified identical absmax).

#define DIM 32
#define RESO 96
#define NPT (RESO * RESO)          // 9216
#define NITER 3
#define ETA 0.5f
#define SCALE 2.88539008f          // BW * log2(e) = 2 * 1.4426950408

#define QB 128                     // queries per block (8 waves x 16)
#define NWAVE 8
#define NQB (NPT / QB)             // 72
#define KSEG 4                     // key segments (grid.y); 144/4 = 36 chunks
#define NCHUNK_TOT (NPT / 64)      // 144 chunks of 64 keys
#define CSEG (NCHUNK_TOT / KSEG)   // 36
#define PSTRIDE 72                 // P-slab row stride in elems (144 B, 16B-aligned)
#define DN (DIM * NPT)

typedef __bf16 bf16_t;
typedef __bf16 v8bf __attribute__((ext_vector_type(8)));
typedef float  v4f  __attribute__((ext_vector_type(4)));

// One-time pack of fp32 X (DIM x NPT) into bf16 row-major (NPT x DIM) and
// bf16 col-major (DIM x NPT); also copies X into d_out slice 0.
__global__ void pack_kernel(const float* __restrict__ X,
                            bf16_t* __restrict__ rows,
                            bf16_t* __restrict__ cols,
                            float* __restrict__ out_copy) {
    int idx = blockIdx.x * 256 + threadIdx.x;
    if (idx >= DN) return;
    int d = idx / NPT;
    int n = idx - d * NPT;
    float v = X[idx];
    cols[idx] = (bf16_t)v;
    rows[n * DIM + d] = (bf16_t)v;
    out_copy[idx] = v;
}

// Fused mean-shift step with split-K last-block reduction.
// Block = 512 thr = 8 waves; wave w owns 16 queries [qb*128 + w*16, +16).
// All waves consume the same 64-key chunk from shared double-buffered LDS
// tiles (one barrier per chunk); wave w stages tile piece w. Block covers
// key segment ks; writes fp32 partials; the last block per qb-group reduces
// them and writes Xnext + next iteration's bf16 rows/cols.
__global__ __launch_bounds__(512, 2)
void msattn_kernel(const float* __restrict__ Xcur,
                   const bf16_t* __restrict__ rows,
                   const bf16_t* __restrict__ cols,
                   float* __restrict__ part_num,
                   float* __restrict__ part_den,
                   float* __restrict__ Xnext,
                   bf16_t* __restrict__ rows_out,
                   bf16_t* __restrict__ cols_out,
                   unsigned int* __restrict__ ctr) {
    // tiles[buf]: [0..2047] = tileA (GEMM1 B, read-order; subtile t at t*512,
    // lane off lane*8): element = key kc+4*l16+t, dims quad*8.. ;
    // [2048..4095] = tileB (GEMM2 B; frag r=(h<<1|g) at 2048+r*512): element =
    // V^T[dim h*16+l16][keys kc+g*32+quad*8..]. Lane i reads base+i*16B: no
    // bank conflicts by construction.
    __shared__ __align__(16) bf16_t tiles[2][4096];
    __shared__ __align__(16) bf16_t pslab[NWAVE][16 * PSTRIDE];
    __shared__ unsigned int lastflag;

    const int tid  = threadIdx.x;
    const int w    = tid >> 6;
    const int lane = tid & 63;
    const int quad = lane >> 4;
    const int l16  = lane & 15;
    const int qb   = blockIdx.x;
    const int ks   = blockIdx.y;
    const int c0   = ks * CSEG;
    const int c1   = c0 + CSEG;
    const int q0w  = qb * QB + w * 16;

    bf16_t* p_lds = pslab[w];

    // A-frag: A[m=l16 (query)][k=quad*8+j (dim)], BW*log2e folded in.
    v8bf afrag;
#pragma unroll
    for (int j = 0; j < 8; ++j) {
        float v = Xcur[(quad * 8 + j) * NPT + q0w + l16];
        afrag[j] = (bf16_t)(v * SCALE);
    }

    // ones B-fragment for MFMA-den (D[q][n] = sum_k P[q][k], all cols equal)
    v8bf ones;
#pragma unroll
    for (int j = 0; j < 8; ++j) ones[j] = (bf16_t)1.0f;

    // Staging: 8 pieces of 1KB per chunk; wave w stages piece w.
    const bf16_t* gsrc;
    int gdelta, ldst;
    if (w < 4) {           // tileA subtile t=w: key c*64+4*l16+w, dims quad*8..
        gsrc = rows + ((size_t)c0 * 64 + 4 * l16 + w) * DIM + quad * 8;
        gdelta = 64 * DIM;
        ldst = w * 512 + lane * 8;
    } else {               // tileB frag r=w-4=(h<<1|g): dim h*16+l16, keys c*64+g*32+quad*8..
        int r = w - 4, h = r >> 1, g = r & 1;
        gsrc = cols + (size_t)(h * 16 + l16) * NPT + c0 * 64 + g * 32 + quad * 8;
        gdelta = 64;
        ldst = 2048 + r * 512 + lane * 8;
    }

    v4f acc0 = {0.f, 0.f, 0.f, 0.f};   // dims 0..15
    v4f acc1 = {0.f, 0.f, 0.f, 0.f};   // dims 16..31
    v4f dden = {0.f, 0.f, 0.f, 0.f};   // den (MFMA-ones)

    // Prologue: stage first chunk into buffer 0.
    {
        v8bf st = *(const v8bf*)gsrc;
        gsrc += gdelta;
        *(v8bf*)&tiles[0][ldst] = st;
    }
    __syncthreads();

    for (int c = c0; c < c1; ++c) {
        const int cc = c - c0;
        const bf16_t* tb = tiles[cc & 1];
        const bool more = (c + 1 < c1);

        v8bf stn;
        if (more) { stn = *(const v8bf*)gsrc; gsrc += gdelta; }

        // --- GEMM1: S subtile t, column n=l16 <-> key kc+4*n+t ---
        v4f s[4];
#pragma unroll
        for (int t = 0; t < 4; ++t) {
            v8bf b = *(const v8bf*)&tb[t * 512 + lane * 8];
            s[t] = __builtin_amdgcn_mfma_f32_16x16x32_bf16(afrag, b,
                                                           (v4f){0.f, 0.f, 0.f, 0.f}, 0, 0, 0);
        }

        // --- exp2 + b64-packed P stores (position 4*l16+t <-> key, identity) ---
#pragma unroll
        for (int r = 0; r < 4; ++r) {
            union { bf16_t h[4]; unsigned long long u; } pk;
#pragma unroll
            for (int t = 0; t < 4; ++t)
                pk.h[t] = (bf16_t)__builtin_amdgcn_exp2f(s[t][r]);
            *(unsigned long long*)&p_lds[(quad * 4 + r) * PSTRIDE + 4 * l16] = pk.u;
        }

        // --- GEMM2 + MFMA-den (wave-local P slab, in-order DS) ---
        v8bf a20 = *(const v8bf*)&p_lds[l16 * PSTRIDE + quad * 8];        // keys 0..31
        v8bf a21 = *(const v8bf*)&p_lds[l16 * PSTRIDE + 32 + quad * 8];   // keys 32..63
        v8bf b00 = *(const v8bf*)&tb[2048 + 0 * 512 + lane * 8];  // dims 0-15,  keys 0-31
        v8bf b01 = *(const v8bf*)&tb[2048 + 1 * 512 + lane * 8];  // dims 0-15,  keys 32-63
        v8bf b10 = *(const v8bf*)&tb[2048 + 2 * 512 + lane * 8];  // dims 16-31, keys 0-31
        v8bf b11 = *(const v8bf*)&tb[2048 + 3 * 512 + lane * 8];  // dims 16-31, keys 32-63
        acc0 = __builtin_amdgcn_mfma_f32_16x16x32_bf16(a20, b00, acc0, 0, 0, 0);
        acc1 = __builtin_amdgcn_mfma_f32_16x16x32_bf16(a20, b10, acc1, 0, 0, 0);
        acc0 = __builtin_amdgcn_mfma_f32_16x16x32_bf16(a21, b01, acc0, 0, 0, 0);
        acc1 = __builtin_amdgcn_mfma_f32_16x16x32_bf16(a21, b11, acc1, 0, 0, 0);
        dden = __builtin_amdgcn_mfma_f32_16x16x32_bf16(a20, ones, dden, 0, 0, 0);
        dden = __builtin_amdgcn_mfma_f32_16x16x32_bf16(a21, ones, dden, 0, 0, 0);

        if (more) *(v8bf*)&tiles[(cc + 1) & 1][ldst] = stn;
        __syncthreads();
    }

    // --- write partials for this segment ---
    float* pn = part_num + (size_t)ks * DN;
#pragma unroll
    for (int r = 0; r < 4; ++r) {
        int gq = q0w + quad * 4 + r;
        pn[(size_t)gq * DIM + l16]      = acc0[r];
        pn[(size_t)gq * DIM + 16 + l16] = acc1[r];
    }
    if (l16 == 0) {
#pragma unroll
        for (int r = 0; r < 4; ++r)
            part_den[ks * NPT + q0w + quad * 4 + r] = dden[r];
    }

    // --- split-K last-block reduction (one release/acquire atomic per block;
    // agent scope pairs writers' releases with the last block's acquire) ---
    __threadfence();     // release our partial writes device-wide
    __syncthreads();     // all waves' stores issued before the atomic
    if (tid == 0) {
        lastflag = __hip_atomic_fetch_add(&ctr[qb], 1u,
                                          __ATOMIC_ACQ_REL,
                                          __HIP_MEMORY_SCOPE_AGENT);
    }
    __syncthreads();
    if (lastflag != KSEG - 1) return;

    // Last block of this qb-group: reduce KSEG segments for queries
    // [qb*QB, +QB), apply eta-step, write Xnext + bf16 repack.
    const int q0b = qb * QB;
    float* sden = (float*)pslab;   // QB floats of scratch (reuse P slab)
    if (tid < QB) {
        float s = 0.f;
#pragma unroll
        for (int ss = 0; ss < KSEG; ++ss)
            s += part_den[ss * NPT + q0b + tid];
        sden[tid] = 1.0f / s;
    }
    __syncthreads();
#pragma unroll
    for (int j = 0; j < (QB * DIM) / 512; ++j) {
        int idx = tid + j * 512;
        int d = idx >> 7;          // QB = 128
        int q = idx & 127;
        int gq = q0b + q;
        float s = 0.f;
#pragma unroll
        for (int ss = 0; ss < KSEG; ++ss)
            s += part_num[(size_t)ss * DN + (size_t)gq * DIM + d];
        float xo = Xcur[d * NPT + gq];
        float xn = ETA * s * sden[q] + (1.0f - ETA) * xo;
        Xnext[d * NPT + gq] = xn;
        cols_out[(size_t)d * NPT + gq] = (bf16_t)xn;
        rows_out[(size_t)gq * DIM + d] = (bf16_t)xn;
    }
}

extern "C" void kernel_launch(void* const* d_in, const int* in_sizes, int n_in,
                              void* d_out, int out_size, void* d_ws, size_t ws_size,
                              hipStream_t stream) {
    const float* x_in = (const float*)d_in[0];
    float* out = (float*)d_out;

    // Workspace: 4 bf16 pack buffers (ping-pong), fp32 partials, counters.
    bf16_t* rows0 = (bf16_t*)d_ws;
    bf16_t* cols0 = rows0 + (size_t)DN;
    bf16_t* rows1 = cols0 + (size_t)DN;
    bf16_t* cols1 = rows1 + (size_t)DN;
    float* part_num = (float*)(cols1 + (size_t)DN);         // KSEG * DN f32
    float* part_den = part_num + (size_t)KSEG * DN;         // KSEG * NPT f32
    size_t ctr_off = (((size_t)(part_den + KSEG * NPT) - (size_t)d_ws) + 255) & ~(size_t)255;
    unsigned int* ctr = (unsigned int*)((char*)d_ws + ctr_off);  // NITER*NQB uints

    hipMemsetAsync(ctr, 0, NITER * NQB * sizeof(unsigned int), stream);

    const int pack_blocks = (DN + 255) / 256;   // 1152
    pack_kernel<<<pack_blocks, 256, 0, stream>>>(x_in, rows0, cols0, out);

    for (int it = 0; it < NITER; ++it) {
        const float* Xcur = (it == 0) ? x_in : out + (size_t)it * DN;
        bf16_t* rin  = (it & 1) ? rows1 : rows0;
        bf16_t* cin  = (it & 1) ? cols1 : cols0;
        bf16_t* rout = (it & 1) ? rows0 : rows1;
        bf16_t* cout = (it & 1) ? cols0 : cols1;
        msattn_kernel<<<dim3(NQB, KSEG), 512, 0, stream>>>(
            Xcur, rin, cin, part_num, part_den,
            out + (size_t)(it + 1) * DN, rout, cout, ctr + it * NQB);
    }
}

// Round 9
// 178.026 us; speedup vs baseline: 2.0910x; 2.0910x over previous
//
#include <hip/hip_runtime.h>
#include <hip/hip_bf16.h>

// Mean-shift: 3 iterations of X <- eta * X @ (K/deg) + (1-eta) * X,
// K = exp(2 * X^T X), D=32, N=9216. Fused attention formulation.
// R9: dispatch-count is the dominant cost (~10us/dispatch; R4 had 7).
// Now 4 dispatches: pack + 3x msattn-with-fused-reduce. The R8 fence
// disaster (agent release = buffer_wbl2, serialized per-XCD L2 scan,
// +90us/dispatch) is replaced by FENCE-FREE publication: fp32 partials
// are published with native LLC atomics (unsafeAtomicAdd -> coherent at
// the LLC, no wbl2), ordered by s_waitcnt vmcnt(0) before a relaxed
// atomicAdd counter; the last block per query-group (arrive-and-check,
// NO polling) reads sums back via unsafeAtomicAdd(p, 0.0f) RMWs
// (guaranteed-coherent reads) and applies the eta-step + bf16 repack.
// Accumulator zeroing is folded into pack (re-poison safe). msattn core
// = R4's proven shape (8 waves x 16 q, shared double-buffered LDS tiles
// in MFMA read order, key-interleaved b64 P stores) + MFMA-ones den.

#define DIM 32
#define RESO 96
#define NPT (RESO * RESO)          // 9216
#define NITER 3
#define ETA 0.5f
#define SCALE 2.88539008f          // BW * log2(e) = 2 * 1.4426950408

#define QB 128                     // queries per block (8 waves x 16)
#define NWAVE 8
#define NQB (NPT / QB)             // 72
#define KSEG 7                     // key segments (grid.y); grid 504 ~ 2 blk/CU
#define NCHUNK_TOT (NPT / 64)      // 144 chunks of 64 keys
#define PSTRIDE 72                 // P-slab row stride in elems (144 B, 16B-aligned)
#define DN (DIM * NPT)
#define ZTOT (NITER * DN + NITER * NPT + NITER * NQB)   // accum dwords to zero

typedef __bf16 bf16_t;
typedef __bf16 v8bf __attribute__((ext_vector_type(8)));
typedef float  v4f  __attribute__((ext_vector_type(4)));

// One-time pack of fp32 X (DIM x NPT) into bf16 row-major (NPT x DIM) and
// bf16 col-major (DIM x NPT); copies X into d_out slice 0; zeroes the
// per-iteration num/den accumulators + counters (harness re-poisons d_ws).
__global__ void pack_kernel(const float* __restrict__ X,
                            bf16_t* __restrict__ rows,
                            bf16_t* __restrict__ cols,
                            float* __restrict__ out_copy,
                            unsigned int* __restrict__ zbase) {
    int idx = blockIdx.x * 256 + threadIdx.x;
    if (idx >= DN) return;
    int d = idx / NPT;
    int n = idx - d * NPT;
    float v = X[idx];
    cols[idx] = (bf16_t)v;
    rows[n * DIM + d] = (bf16_t)v;
    out_copy[idx] = v;
    for (int z = idx; z < ZTOT; z += DN) zbase[z] = 0u;
}

// Fused mean-shift step with fence-free split-K reduction.
// Block = 512 thr = 8 waves; wave w owns 16 queries [qb*128 + w*16, +16).
// All waves consume the same 64-key chunk from shared double-buffered LDS
// tiles (one barrier per chunk); wave w stages tile piece w. Block covers
// key segment ks; publishes partials via LLC-coherent fp32 atomic adds;
// last block per qb-group finalizes.
__global__ __launch_bounds__(512, 2)
void msattn_kernel(const float* __restrict__ Xcur,
                   const bf16_t* __restrict__ rows,
                   const bf16_t* __restrict__ cols,
                   float* __restrict__ num_acc,     // NPT x DIM (q-major)
                   float* __restrict__ den_acc,     // NPT
                   float* __restrict__ Xnext,
                   bf16_t* __restrict__ rows_out,
                   bf16_t* __restrict__ cols_out,
                   unsigned int* __restrict__ ctr) {
    // tiles[buf]: [0..2047] = tileA (GEMM1 B, read-order; subtile t at t*512,
    // lane off lane*8): element = key kc+4*l16+t, dims quad*8.. ;
    // [2048..4095] = tileB (GEMM2 B; frag r=(h<<1|g) at 2048+r*512): element =
    // V^T[dim h*16+l16][keys kc+g*32+quad*8..]. Lane i reads base+i*16B: no
    // bank conflicts by construction.
    __shared__ __align__(16) bf16_t tiles[2][4096];
    __shared__ __align__(16) bf16_t pslab[NWAVE][16 * PSTRIDE];
    __shared__ unsigned int lastflag;

    const int tid  = threadIdx.x;
    const int w    = tid >> 6;
    const int lane = tid & 63;
    const int quad = lane >> 4;
    const int l16  = lane & 15;
    const int qb   = blockIdx.x;
    const int ks   = blockIdx.y;
    const int c0   = (NCHUNK_TOT * ks) / KSEG;
    const int c1   = (NCHUNK_TOT * (ks + 1)) / KSEG;
    const int q0w  = qb * QB + w * 16;

    bf16_t* p_lds = pslab[w];

    // A-frag: A[m=l16 (query)][k=quad*8+j (dim)], BW*log2e folded in.
    v8bf afrag;
#pragma unroll
    for (int j = 0; j < 8; ++j) {
        float v = Xcur[(quad * 8 + j) * NPT + q0w + l16];
        afrag[j] = (bf16_t)(v * SCALE);
    }

    // ones B-fragment for MFMA-den (D[q][n] = sum_k P[q][k], all cols equal)
    v8bf ones;
#pragma unroll
    for (int j = 0; j < 8; ++j) ones[j] = (bf16_t)1.0f;

    // Staging: 8 pieces of 1KB per chunk; wave w stages piece w.
    const bf16_t* gsrc;
    int gdelta, ldst;
    if (w < 4) {           // tileA subtile t=w: key c*64+4*l16+w, dims quad*8..
        gsrc = rows + ((size_t)c0 * 64 + 4 * l16 + w) * DIM + quad * 8;
        gdelta = 64 * DIM;
        ldst = w * 512 + lane * 8;
    } else {               // tileB frag r=w-4=(h<<1|g): dim h*16+l16, keys c*64+g*32+quad*8..
        int r = w - 4, h = r >> 1, g = r & 1;
        gsrc = cols + (size_t)(h * 16 + l16) * NPT + c0 * 64 + g * 32 + quad * 8;
        gdelta = 64;
        ldst = 2048 + r * 512 + lane * 8;
    }

    v4f acc0 = {0.f, 0.f, 0.f, 0.f};   // dims 0..15
    v4f acc1 = {0.f, 0.f, 0.f, 0.f};   // dims 16..31
    v4f dden = {0.f, 0.f, 0.f, 0.f};   // den (MFMA-ones)

    // Prologue: stage first chunk into buffer 0.
    {
        v8bf st = *(const v8bf*)gsrc;
        gsrc += gdelta;
        *(v8bf*)&tiles[0][ldst] = st;
    }
    __syncthreads();

    for (int c = c0; c < c1; ++c) {
        const int cc = c - c0;
        const bf16_t* tb = tiles[cc & 1];
        const bool more = (c + 1 < c1);

        v8bf stn;
        if (more) { stn = *(const v8bf*)gsrc; gsrc += gdelta; }

        // --- GEMM1: S subtile t, column n=l16 <-> key kc+4*n+t ---
        v4f s[4];
#pragma unroll
        for (int t = 0; t < 4; ++t) {
            v8bf b = *(const v8bf*)&tb[t * 512 + lane * 8];
            s[t] = __builtin_amdgcn_mfma_f32_16x16x32_bf16(afrag, b,
                                                           (v4f){0.f, 0.f, 0.f, 0.f}, 0, 0, 0);
        }

        // --- exp2 + b64-packed P stores (position 4*l16+t <-> key, identity) ---
#pragma unroll
        for (int r = 0; r < 4; ++r) {
            union { bf16_t h[4]; unsigned long long u; } pk;
#pragma unroll
            for (int t = 0; t < 4; ++t)
                pk.h[t] = (bf16_t)__builtin_amdgcn_exp2f(s[t][r]);
            *(unsigned long long*)&p_lds[(quad * 4 + r) * PSTRIDE + 4 * l16] = pk.u;
        }

        // --- GEMM2 + MFMA-den (wave-local P slab, in-order DS) ---
        v8bf a20 = *(const v8bf*)&p_lds[l16 * PSTRIDE + quad * 8];        // keys 0..31
        v8bf a21 = *(const v8bf*)&p_lds[l16 * PSTRIDE + 32 + quad * 8];   // keys 32..63
        v8bf b00 = *(const v8bf*)&tb[2048 + 0 * 512 + lane * 8];  // dims 0-15,  keys 0-31
        v8bf b01 = *(const v8bf*)&tb[2048 + 1 * 512 + lane * 8];  // dims 0-15,  keys 32-63
        v8bf b10 = *(const v8bf*)&tb[2048 + 2 * 512 + lane * 8];  // dims 16-31, keys 0-31
        v8bf b11 = *(const v8bf*)&tb[2048 + 3 * 512 + lane * 8];  // dims 16-31, keys 32-63
        acc0 = __builtin_amdgcn_mfma_f32_16x16x32_bf16(a20, b00, acc0, 0, 0, 0);
        acc1 = __builtin_amdgcn_mfma_f32_16x16x32_bf16(a20, b10, acc1, 0, 0, 0);
        acc0 = __builtin_amdgcn_mfma_f32_16x16x32_bf16(a21, b01, acc0, 0, 0, 0);
        acc1 = __builtin_amdgcn_mfma_f32_16x16x32_bf16(a21, b11, acc1, 0, 0, 0);
        dden = __builtin_amdgcn_mfma_f32_16x16x32_bf16(a20, ones, dden, 0, 0, 0);
        dden = __builtin_amdgcn_mfma_f32_16x16x32_bf16(a21, ones, dden, 0, 0, 0);

        if (more) *(v8bf*)&tiles[(cc + 1) & 1][ldst] = stn;
        __syncthreads();
    }

    // --- publish partials: native LLC fp32 atomic adds (coherent at the
    // device coherence point; NO release fence / wbl2 needed) ---
#pragma unroll
    for (int r = 0; r < 4; ++r) {
        int gq = q0w + quad * 4 + r;
        unsafeAtomicAdd(&num_acc[(size_t)gq * DIM + l16],      acc0[r]);
        unsafeAtomicAdd(&num_acc[(size_t)gq * DIM + 16 + l16], acc1[r]);
    }
    if (l16 == 0) {
#pragma unroll
        for (int r = 0; r < 4; ++r)
            unsafeAtomicAdd(&den_acc[q0w + quad * 4 + r], dden[r]);
    }
    // Ensure this wave's adds are acked at the LLC before signaling arrival.
    asm volatile("s_waitcnt vmcnt(0)" ::: "memory");
    __syncthreads();
    if (tid == 0) lastflag = atomicAdd(&ctr[qb], 1u);   // relaxed, no fence
    __syncthreads();
    if (lastflag != KSEG - 1) return;

    // --- last block of qb-group: coherent read-back via atomic RMW (+0.0f),
    // eta-step, write Xnext + next iteration's bf16 rows/cols ---
    const int q0b = qb * QB;
    float* sden = (float*)pslab;   // QB floats of scratch (P slab is dead)
    if (tid < QB) {
        float s = unsafeAtomicAdd(&den_acc[q0b + tid], 0.0f);
        sden[tid] = 1.0f / s;
    }
    __syncthreads();
#pragma unroll
    for (int j = 0; j < (QB * DIM) / 512; ++j) {
        int idx = tid + j * 512;
        int d = idx >> 7;          // QB = 128
        int q = idx & 127;
        int gq = q0b + q;
        float s = unsafeAtomicAdd(&num_acc[(size_t)gq * DIM + d], 0.0f);
        float xo = Xcur[d * NPT + gq];
        float xn = ETA * s * sden[q] + (1.0f - ETA) * xo;
        Xnext[d * NPT + gq] = xn;
        cols_out[(size_t)d * NPT + gq] = (bf16_t)xn;
        rows_out[(size_t)gq * DIM + d] = (bf16_t)xn;
    }
}

extern "C" void kernel_launch(void* const* d_in, const int* in_sizes, int n_in,
                              void* d_out, int out_size, void* d_ws, size_t ws_size,
                              hipStream_t stream) {
    const float* x_in = (const float*)d_in[0];
    float* out = (float*)d_out;

    // Workspace: 4 bf16 pack buffers (ping-pong) + per-iteration accumulators.
    bf16_t* rows0 = (bf16_t*)d_ws;
    bf16_t* cols0 = rows0 + (size_t)DN;
    bf16_t* rows1 = cols0 + (size_t)DN;
    bf16_t* cols1 = rows1 + (size_t)DN;
    unsigned int* zbase = (unsigned int*)(cols1 + (size_t)DN);
    float* num_base = (float*)zbase;                        // NITER * DN
    float* den_base = num_base + (size_t)NITER * DN;        // NITER * NPT
    unsigned int* ctr_base = (unsigned int*)(den_base + (size_t)NITER * NPT); // NITER * NQB

    const int pack_blocks = (DN + 255) / 256;   // 1152
    pack_kernel<<<pack_blocks, 256, 0, stream>>>(x_in, rows0, cols0, out, zbase);

    for (int it = 0; it < NITER; ++it) {
        const float* Xcur = (it == 0) ? x_in : out + (size_t)it * DN;
        bf16_t* rin  = (it & 1) ? rows1 : rows0;
        bf16_t* cin  = (it & 1) ? cols1 : cols0;
        bf16_t* rout = (it & 1) ? rows0 : rows1;
        bf16_t* cout = (it & 1) ? cols0 : cols1;
        msattn_kernel<<<dim3(NQB, KSEG), 512, 0, stream>>>(
            Xcur, rin, cin,
            num_base + (size_t)it * DN, den_base + (size_t)it * NPT,
            out + (size_t)(it + 1) * DN, rout, cout,
            ctr_base + it * NQB);
    }
}